// Round 7
// baseline (182.147 us; speedup 1.0000x reference)
//
#include <hip/hip_runtime.h>
#include <math.h>

#define Nn 98304
#define Ee 1572864
#define Cc 64
#define Hh 32
#define HB 256              // phase-1 blocks
#define EPB (Ee / HB)       // 6144 edges per block
#define NST 384             // super-tiles
#define SN 256              // nodes per super-tile (d>>8)
#define CAP_ST 4800         // edges per super-tile region (mean 4096, sigma~64 -> +11 sigma)
#define GN 64               // nodes per fused gather+final block

typedef float v2f __attribute__((ext_vector_type(2)));

// ws layout (4B units):
//   dinv[Nn] | gb[Nn*32] (bf16 x64/row) | rowOff[Nn] | rowEnd[Nn]
//   | aux[HB*NST] | ebuf[Ee] | srcs[NST*CAP_ST]

// int64 little-endian indices (< 2^31) -> odd 32-bit words are 0. All threads
// check the SAME 16 words -> deterministic agreement.
__device__ __forceinline__ int detect64(const void* ei) {
    const unsigned int* u = (const unsigned int*)ei;
    int is64 = 1;
    #pragma unroll
    for (int i = 0; i < 16; ++i) is64 &= (u[2 * i + 1] == 0u);
    return is64;
}

__device__ __forceinline__ int load_idx(const void* ei, long e, int is64) {
    if (is64) return (int)((const long long*)ei)[e];
    return ((const int*)ei)[e];
}

__device__ __forceinline__ unsigned short f2bf(float x) {
    union { float f; unsigned int u; } v; v.f = x;
    unsigned int r = v.u + 0x7FFFu + ((v.u >> 16) & 1u);   // RNE
    return (unsigned short)(r >> 16);
}

// unpack one u32 = 2 bf16 channels -> float2
__device__ __forceinline__ v2f up2(unsigned int u) {
    union { unsigned int i; float f; } lo, hi;
    lo.i = u << 16; hi.i = u & 0xFFFF0000u;
    v2f r; r.x = lo.f; r.y = hi.f;
    return r;
}
// packed accumulate: 4 v_pk_add_f32 per uint4 (bit-identical per-channel adds)
__device__ __forceinline__ void accv(v2f A[4], uint4 u) {
    A[0] += up2(u.x); A[1] += up2(u.y); A[2] += up2(u.z); A[3] += up2(u.w);
}
__device__ __forceinline__ void setv(v2f A[4], uint4 u) {
    A[0] = up2(u.x); A[1] = up2(u.y); A[2] = up2(u.z); A[3] = up2(u.w);
}

// Phase 1: block-local counting sort of EPB edges by SUPER-TILE (384 buckets,
// 256 nodes each). Block-private compact write (no global atomics, no
// scattered writes). aux[b*NST+st] = localOff(16b) | cnt<<16.
__global__ __launch_bounds__(1024) void k_p1(const void* __restrict__ ei,
                                             unsigned int* __restrict__ aux,
                                             unsigned int* __restrict__ ebuf) {
    __shared__ unsigned int hl[NST];
    __shared__ unsigned int cur[NST];
    int t = threadIdx.x, b = blockIdx.x;
    if (t < NST) hl[t] = 0;
    __syncthreads();
    int is64 = detect64(ei);
    long e0 = (long)b * EPB;
    #pragma unroll
    for (int i = 0; i < EPB / 1024; ++i) {     // 6 iters
        int d = load_idx(ei, (long)Ee + e0 + i * 1024 + t, is64);
        atomicAdd(&hl[d >> 8], 1u);            // d / SN
    }
    __syncthreads();
    if (t < NST) cur[t] = hl[t];
    __syncthreads();
    // inclusive Hillis-Steele scan over 384
    for (int s = 1; s < NST; s <<= 1) {
        unsigned int v = (t < NST && t >= s) ? cur[t - s] : 0u;
        __syncthreads();
        if (t < NST) cur[t] += v;
        __syncthreads();
    }
    if (t < NST) {
        unsigned int ex = cur[t] - hl[t];      // exclusive
        aux[(long)b * NST + t] = ex | (hl[t] << 16);
        cur[t] = ex;                           // reuse as cursor
    }
    __syncthreads();
    #pragma unroll
    for (int i = 0; i < EPB / 1024; ++i) {     // re-read: block slice L2-hot
        long e = e0 + i * 1024 + t;
        int s = load_idx(ei, e, is64);
        int d = load_idx(ei, (long)Ee + e, is64);
        unsigned int pos = atomicAdd(&cur[d >> 8], 1u);   // LDS atomic
        ebuf[(long)b * EPB + pos] = (unsigned int)s | ((unsigned int)(d & (SN - 1)) << 17);
    }
}

// Phase 2: per super-tile, 512 threads. Segmented COALESCED staging via binary
// search over the inclusive run prefix, then count 256 local dsts
// (-> dinv, rowOff, rowEnd) and scatter src into the packed srcs region.
__global__ __launch_bounds__(512) void k_p2(const unsigned int* __restrict__ aux,
                                            const unsigned int* __restrict__ ebuf,
                                            unsigned int* __restrict__ rowOff,
                                            unsigned int* __restrict__ rowEnd,
                                            float* __restrict__ dinv,
                                            unsigned int* __restrict__ srcs) {
    __shared__ unsigned int stage[CAP_ST];   // 18.75 KB
    __shared__ unsigned int rbI[HB];         // inclusive prefix of run counts
    __shared__ unsigned int rof[HB];         // per-block run offset
    __shared__ unsigned int cnt[SN];
    __shared__ unsigned int sc[SN];
    __shared__ unsigned int cur[SN];
    int t = threadIdx.x, st = blockIdx.x;
    if (t < HB) {
        unsigned int av = aux[(long)t * NST + st];
        rof[t] = av & 0xFFFFu;
        rbI[t] = av >> 16;
    }
    if (t < SN) cnt[t] = 0;
    __syncthreads();
    for (int s = 1; s < HB; s <<= 1) {          // inclusive scan over 256
        unsigned int v = (t < HB && t >= s) ? rbI[t - s] : 0u;
        __syncthreads();
        if (t < HB) rbI[t] += v;
        __syncthreads();
    }
    int total = (int)rbI[HB - 1];
    for (int i = t; i < total; i += 512) {
        int lo = 0, hi = HB - 1;                // min b with rbI[b] > i
        while (lo < hi) {
            int mid = (lo + hi) >> 1;
            if (rbI[mid] > (unsigned int)i) hi = mid; else lo = mid + 1;
        }
        unsigned int ex = lo ? rbI[lo - 1] : 0u;
        stage[i] = ebuf[(long)lo * EPB + rof[lo] + ((unsigned int)i - ex)];
    }
    __syncthreads();
    for (int i = t; i < total; i += 512)
        atomicAdd(&cnt[stage[i] >> 17], 1u);
    __syncthreads();
    if (t < SN) sc[t] = cnt[t];
    __syncthreads();
    #pragma unroll
    for (int off = 1; off < SN; off <<= 1) {
        unsigned int v = (t < SN && t >= off) ? sc[t - off] : 0u;
        __syncthreads();
        if (t < SN) sc[t] += v;
        __syncthreads();
    }
    if (t < SN) {
        unsigned int start = (unsigned int)(st * CAP_ST) + sc[t] - cnt[t];
        rowOff[(long)st * SN + t] = start;
        rowEnd[(long)st * SN + t] = start + cnt[t];
        cur[t] = start;
        dinv[(long)st * SN + t] = rsqrtf((float)(cnt[t] + 1));   // +1 self-loop
    }
    __syncthreads();
    for (int i = t; i < total; i += 512) {
        unsigned int u = stage[i];
        unsigned int pos = atomicAdd(&cur[u >> 17], 1u);
        srcs[pos] = u & 0x1FFFFu;
    }
}

// gb = bf16( (state @ conv_W) * dinv[row] )
__global__ __launch_bounds__(256) void k_gemm(const float* __restrict__ state,
                                              const float* __restrict__ W,
                                              const float* __restrict__ dinv,
                                              unsigned short* __restrict__ gb) {
    __shared__ float Wl[64 * 64];       // [k][c]
    __shared__ float Al[64 * 68];       // [r][k], stride 68
    int t = threadIdx.x;
    long n0 = (long)blockIdx.x * 64;

    const float4* W4 = (const float4*)W;
    float4* Wl4 = (float4*)Wl;
    #pragma unroll
    for (int i = 0; i < 4; ++i) Wl4[i * 256 + t] = W4[i * 256 + t];

    const float4* S4 = (const float4*)(state) + n0 * 16;
    #pragma unroll
    for (int i = 0; i < 4; ++i) {
        int f4 = t + i * 256;
        int r = f4 >> 4, k0 = (f4 & 15) * 4;
        *(float4*)(Al + r * 68 + k0) = S4[f4];
    }
    __syncthreads();

    int r0 = (t >> 4) * 4;
    int c0 = (t & 15) * 4;
    float acc[4][4] = {{0.f}};
    #pragma unroll
    for (int kk = 0; kk < 64; kk += 4) {
        float4 a4[4], w4[4];
        #pragma unroll
        for (int i = 0; i < 4; ++i) a4[i] = *(const float4*)(Al + (r0 + i) * 68 + kk);
        #pragma unroll
        for (int j = 0; j < 4; ++j) w4[j] = *(const float4*)(Wl + (kk + j) * 64 + c0);
        const float* aa = (const float*)a4;
        const float* ww = (const float*)w4;
        #pragma unroll
        for (int i = 0; i < 4; ++i)
            #pragma unroll
            for (int j = 0; j < 4; ++j) {
                float av = aa[i * 4 + j];
                #pragma unroll
                for (int c = 0; c < 4; ++c)
                    acc[i][c] = fmaf(av, ww[j * 4 + c], acc[i][c]);
            }
    }
    #pragma unroll
    for (int i = 0; i < 4; ++i) {
        long n = n0 + r0 + i;
        float dv = dinv[n];
        ushort4 o;
        o.x = f2bf(acc[i][0] * dv); o.y = f2bf(acc[i][1] * dv);
        o.z = f2bf(acc[i][2] * dv); o.w = f2bf(acc[i][3] * dv);
        *(ushort4*)(gb + n * 64 + c0) = o;
    }
}

// Fused gather + epilogue MLP. 512 threads (8 waves), GN=64 nodes/block.
// Gather: DEGREE-SORTED group->node assignment (rank sort of the block's 64
// node degrees; waves get adjacent-degree nodes -> divergence waste ~1.05x vs
// ~1.6x random). 8 lanes per node, uint4 per lane, 2-QUAD software pipeline
// (8 rows in flight). Accumulate via float2 ext-vectors -> v_pk_add_f32.
// FP order per node = edge-list order, unchanged vs R5/R6.
// One block barrier after gather (perm crosses waves); MLP phases wave-local.
__global__ __launch_bounds__(512) void k_gf(const unsigned int* __restrict__ rowOff,
                                            const unsigned int* __restrict__ rowEnd,
                                            const unsigned int* __restrict__ srcs,
                                            const unsigned short* __restrict__ gb,
                                            const float* __restrict__ dinv,
                                            const float* __restrict__ state,
                                            const float* __restrict__ conv_b,
                                            const float* __restrict__ W1,
                                            const float* __restrict__ b1,
                                            const float* __restrict__ W2,
                                            const float* __restrict__ b2,
                                            const float* __restrict__ W3,
                                            const float* __restrict__ b3,
                                            float* __restrict__ out) {
    __shared__ float sa[GN * 68];       // agg rows then x then h2 (17.4 KB)
    __shared__ float hs[GN * 34];       // h1 rows (8.7 KB)
    __shared__ float sW1[Cc * Hh];
    __shared__ float sW2[Hh * Hh];
    __shared__ float sW3[Hh], sb1[Hh], sb2[Hh], scb[Cc];
    __shared__ float sb3;
    __shared__ int deg[GN];
    __shared__ unsigned short perm[GN]; // perm[rank] = node slot
    int t = threadIdx.x;
    int wave = t >> 6, lane = t & 63;
    long n0 = (long)blockIdx.x * GN;

    for (int i = t; i < Cc * Hh; i += 512) sW1[i] = W1[i];
    for (int i = t; i < Hh * Hh; i += 512) sW2[i] = W2[i];
    if (t < Hh) { sW3[t] = W3[t]; sb1[t] = b1[t]; sb2[t] = b2[t]; }
    if (t >= 64 && t < 128) scb[t - 64] = conv_b[t - 64];
    if (t == 511) sb3 = b3[0];
    if (t < GN) deg[t] = (int)(rowEnd[n0 + t] - rowOff[n0 + t]);
    __syncthreads();                    // weights + degrees visible

    if (t < GN) {                       // rank sort (descending, idx tiebreak)
        int d = deg[t], r = 0;
        #pragma unroll
        for (int k = 0; k < GN; ++k) {
            int dk = deg[k];
            r += (dk > d || (dk == d && k < t)) ? 1 : 0;
        }
        perm[r] = (unsigned short)t;
    }
    __syncthreads();                    // perm visible

    // --- gather phase: group G handles node perm[G]; 2-quad pipeline ---
    {
        int G = wave * 8 + (lane >> 3); // group id in block
        int cs = lane & 7;              // 16B chunk: channels cs*8 .. cs*8+7
        int jn = (int)perm[G];          // node slot (degree-sorted)
        long n = n0 + jn;
        int ptr = (int)rowOff[n];
        int end = (int)rowEnd[n];
        float dv = dinv[n];
        const uint4* gb4 = (const uint4*)gb;    // row n = gb4[n*8 + cs]

        v2f A[4];
        setv(A, gb4[n * 8 + cs]);               // self-loop row

        int cnt = end - ptr;
        uint4 r0, r1, r2, r3, q0, q1, q2, q3;   // two in-flight quads
        if (cnt >= 4) {
            int s0 = (int)srcs[ptr],     s1 = (int)srcs[ptr + 1];
            int s2 = (int)srcs[ptr + 2], s3 = (int)srcs[ptr + 3];
            r0 = gb4[(long)s0 * 8 + cs]; r1 = gb4[(long)s1 * 8 + cs];
            r2 = gb4[(long)s2 * 8 + cs]; r3 = gb4[(long)s3 * 8 + cs];
        }
        if (cnt >= 8) {
            int s0 = (int)srcs[ptr + 4], s1 = (int)srcs[ptr + 5];
            int s2 = (int)srcs[ptr + 6], s3 = (int)srcs[ptr + 7];
            q0 = gb4[(long)s0 * 8 + cs]; q1 = gb4[(long)s1 * 8 + cs];
            q2 = gb4[(long)s2 * 8 + cs]; q3 = gb4[(long)s3 * 8 + cs];
        }
        while (cnt >= 16) {
            int a0 = (int)srcs[ptr + 8],  a1 = (int)srcs[ptr + 9];
            int a2 = (int)srcs[ptr + 10], a3 = (int)srcs[ptr + 11];
            accv(A, r0); accv(A, r1); accv(A, r2); accv(A, r3);
            r0 = gb4[(long)a0 * 8 + cs]; r1 = gb4[(long)a1 * 8 + cs];
            r2 = gb4[(long)a2 * 8 + cs]; r3 = gb4[(long)a3 * 8 + cs];
            int b0 = (int)srcs[ptr + 12], b1_ = (int)srcs[ptr + 13];
            int b2_ = (int)srcs[ptr + 14], b3_ = (int)srcs[ptr + 15];
            accv(A, q0); accv(A, q1); accv(A, q2); accv(A, q3);
            q0 = gb4[(long)b0 * 8 + cs];  q1 = gb4[(long)b1_ * 8 + cs];
            q2 = gb4[(long)b2_ * 8 + cs]; q3 = gb4[(long)b3_ * 8 + cs];
            ptr += 8; cnt -= 8;
        }
        if (cnt >= 12) {                // r=quad@ptr, q=quad@ptr+4, one more
            int a0 = (int)srcs[ptr + 8],  a1 = (int)srcs[ptr + 9];
            int a2 = (int)srcs[ptr + 10], a3 = (int)srcs[ptr + 11];
            accv(A, r0); accv(A, r1); accv(A, r2); accv(A, r3);
            r0 = gb4[(long)a0 * 8 + cs]; r1 = gb4[(long)a1 * 8 + cs];
            r2 = gb4[(long)a2 * 8 + cs]; r3 = gb4[(long)a3 * 8 + cs];
            accv(A, q0); accv(A, q1); accv(A, q2); accv(A, q3);
            accv(A, r0); accv(A, r1); accv(A, r2); accv(A, r3);
            ptr += 12; cnt -= 12;
        } else if (cnt >= 8) {
            accv(A, r0); accv(A, r1); accv(A, r2); accv(A, r3);
            accv(A, q0); accv(A, q1); accv(A, q2); accv(A, q3);
            ptr += 8; cnt -= 8;
        } else if (cnt >= 4) {
            accv(A, r0); accv(A, r1); accv(A, r2); accv(A, r3);
            ptr += 4; cnt -= 4;
        }
        while (cnt > 0) {               // scalar tail (<4 edges)
            int s0 = (int)srcs[ptr];
            uint4 u0 = gb4[(long)s0 * 8 + cs];
            accv(A, u0);
            ++ptr; --cnt;
        }

        float* r = sa + jn * 68 + cs * 8;       // 16B-aligned (68*4=272=17*16)
        float4 lo, hi;
        lo.x = A[0].x * dv; lo.y = A[0].y * dv;
        lo.z = A[1].x * dv; lo.w = A[1].y * dv;
        hi.x = A[2].x * dv; hi.y = A[2].y * dv;
        hi.z = A[3].x * dv; hi.w = A[3].y * dv;
        *(float4*)r = lo;
        *(float4*)(r + 4) = hi;
    }
    __syncthreads();    // perm crosses waves: all sa rows complete

    // --- 2a: x = relu(agg + cb) + state (wave-local: j = t>>3 in [8w,8w+8)) ---
    {
        int j = t >> 3, o = t & 7;
        long n = n0 + j;
        int k0 = o * 8;
        const float4* sp4 = (const float4*)(state + n * 64 + k0);
        float4 s0 = sp4[0], s1 = sp4[1];
        float* r = sa + j * 68 + k0;
        r[0] = fmaxf(r[0] + scb[k0 + 0], 0.f) + s0.x;
        r[1] = fmaxf(r[1] + scb[k0 + 1], 0.f) + s0.y;
        r[2] = fmaxf(r[2] + scb[k0 + 2], 0.f) + s0.z;
        r[3] = fmaxf(r[3] + scb[k0 + 3], 0.f) + s0.w;
        r[4] = fmaxf(r[4] + scb[k0 + 4], 0.f) + s1.x;
        r[5] = fmaxf(r[5] + scb[k0 + 5], 0.f) + s1.y;
        r[6] = fmaxf(r[6] + scb[k0 + 6], 0.f) + s1.z;
        r[7] = fmaxf(r[7] + scb[k0 + 7], 0.f) + s1.w;
    }
    __builtin_amdgcn_wave_barrier();

    // --- 2b: h1 = relu(x@W1 + b1) (wave-local) ---
    {
        int j = t >> 3, o = t & 7;
        int c0 = o * 4;
        float a0 = sb1[c0], a1 = sb1[c0 + 1], a2 = sb1[c0 + 2], a3 = sb1[c0 + 3];
        #pragma unroll
        for (int k = 0; k < Cc; ++k) {
            float xv = sa[j * 68 + k];
            float4 w = *(const float4*)(sW1 + k * Hh + c0);
            a0 = fmaf(xv, w.x, a0); a1 = fmaf(xv, w.y, a1);
            a2 = fmaf(xv, w.z, a2); a3 = fmaf(xv, w.w, a3);
        }
        float* r = hs + j * 34 + c0;
        r[0] = fmaxf(a0, 0.f); r[1] = fmaxf(a1, 0.f);
        r[2] = fmaxf(a2, 0.f); r[3] = fmaxf(a3, 0.f);
    }
    __builtin_amdgcn_wave_barrier();

    // --- 2c: h2 = relu(h1@W2 + b2) -> sa (wave-local) ---
    {
        int j = t >> 3, o = t & 7;
        int c0 = o * 4;
        float a0 = sb2[c0], a1 = sb2[c0 + 1], a2 = sb2[c0 + 2], a3 = sb2[c0 + 3];
        #pragma unroll
        for (int k = 0; k < Hh; ++k) {
            float xv = hs[j * 34 + k];
            float4 w = *(const float4*)(sW2 + k * Hh + c0);
            a0 = fmaf(xv, w.x, a0); a1 = fmaf(xv, w.y, a1);
            a2 = fmaf(xv, w.z, a2); a3 = fmaf(xv, w.w, a3);
        }
        float* r = sa + j * 68 + c0;
        r[0] = fmaxf(a0, 0.f); r[1] = fmaxf(a1, 0.f);
        r[2] = fmaxf(a2, 0.f); r[3] = fmaxf(a3, 0.f);
    }
    __builtin_amdgcn_wave_barrier();

    // --- 2d: y = h2@W3 + b3; softplus (wave-local: 8 lanes per node, shfl) ---
    {
        int g = lane >> 3, o = lane & 7;
        int j = wave * 8 + g;
        int k0 = o * 4;
        float y = 0.f;
        #pragma unroll
        for (int k = 0; k < 4; ++k) y = fmaf(sa[j * 68 + k0 + k], sW3[k0 + k], y);
        y += __shfl_xor(y, 1, 64);
        y += __shfl_xor(y, 2, 64);
        y += __shfl_xor(y, 4, 64);
        if (o == 0) {
            y += sb3;
            float sp = fmaxf(y, 0.f) + log1pf(expf(-fabsf(y)));
            out[n0 + j] = sp + 1e-20f;
        }
    }
}

extern "C" void kernel_launch(void* const* d_in, const int* in_sizes, int n_in,
                              void* d_out, int out_size, void* d_ws, size_t ws_size,
                              hipStream_t stream) {
    const float* state  = (const float*)d_in[0];
    const void*  ei     = d_in[1];
    const float* conv_W = (const float*)d_in[2];
    const float* conv_b = (const float*)d_in[3];
    const float* W1 = (const float*)d_in[4];
    const float* b1 = (const float*)d_in[5];
    const float* W2 = (const float*)d_in[6];
    const float* b2 = (const float*)d_in[7];
    const float* W3 = (const float*)d_in[8];
    const float* b3 = (const float*)d_in[9];
    float* out = (float*)d_out;

    float*          dinv   = (float*)d_ws;
    unsigned short* gb     = (unsigned short*)(dinv + Nn);
    unsigned int*   rowOff = (unsigned int*)(gb + (size_t)Nn * 64);
    unsigned int*   rowEnd = rowOff + Nn;
    unsigned int*   aux    = rowEnd + Nn;                    // HB*NST
    unsigned int*   ebuf   = aux + (size_t)HB * NST;         // Ee
    unsigned int*   srcs   = ebuf + Ee;                      // NST*CAP_ST

    k_p1<<<HB, 1024, 0, stream>>>(ei, aux, ebuf);
    k_p2<<<NST, 512, 0, stream>>>(aux, ebuf, rowOff, rowEnd, dinv, srcs);
    k_gemm<<<Nn / 64, 256, 0, stream>>>(state, conv_W, dinv, gb);
    k_gf<<<Nn / GN, 512, 0, stream>>>(rowOff, rowEnd, srcs, gb, dinv, state, conv_b,
                                      W1, b1, W2, b2, W3, b3, out);
}

// Round 8
// 166.077 us; speedup vs baseline: 1.0968x; 1.0968x over previous
//
#include <hip/hip_runtime.h>
#include <math.h>

#define Nn 98304
#define Ee 1572864
#define Cc 64
#define Hh 32
#define HB 256              // phase-1 blocks
#define EPB (Ee / HB)       // 6144 edges per block
#define NST 384             // super-tiles
#define SN 256              // nodes per super-tile (d>>8)
#define CAP_ST 4800         // edges per super-tile region (mean 4096, sigma~64 -> +11 sigma)
#define GN 64               // nodes per fused gather+final block

// ws layout (4B units):
//   dinv[Nn] | gb[Nn*32] (bf16 x64/row) | rowOff[Nn] | rowEnd[Nn]
//   | aux[HB*NST] | ebuf[Ee] | srcs[NST*CAP_ST]

// int64 little-endian indices (< 2^31) -> odd 32-bit words are 0. All threads
// check the SAME 16 words -> deterministic agreement.
__device__ __forceinline__ int detect64(const void* ei) {
    const unsigned int* u = (const unsigned int*)ei;
    int is64 = 1;
    #pragma unroll
    for (int i = 0; i < 16; ++i) is64 &= (u[2 * i + 1] == 0u);
    return is64;
}

__device__ __forceinline__ int load_idx(const void* ei, long e, int is64) {
    if (is64) return (int)((const long long*)ei)[e];
    return ((const int*)ei)[e];
}

__device__ __forceinline__ unsigned short f2bf(float x) {
    union { float f; unsigned int u; } v; v.f = x;
    unsigned int r = v.u + 0x7FFFu + ((v.u >> 16) & 1u);   // RNE
    return (unsigned short)(r >> 16);
}

// unpack uint4 = 8 bf16 channels, accumulate
__device__ __forceinline__ void acc_u4(float a[8], uint4 u) {
    union { unsigned int i; float f; } w;
    w.i = u.x << 16;         a[0] += w.f;
    w.i = u.x & 0xFFFF0000u; a[1] += w.f;
    w.i = u.y << 16;         a[2] += w.f;
    w.i = u.y & 0xFFFF0000u; a[3] += w.f;
    w.i = u.z << 16;         a[4] += w.f;
    w.i = u.z & 0xFFFF0000u; a[5] += w.f;
    w.i = u.w << 16;         a[6] += w.f;
    w.i = u.w & 0xFFFF0000u; a[7] += w.f;
}
__device__ __forceinline__ void set_u4(float a[8], uint4 u) {
    union { unsigned int i; float f; } w;
    w.i = u.x << 16;         a[0] = w.f;
    w.i = u.x & 0xFFFF0000u; a[1] = w.f;
    w.i = u.y << 16;         a[2] = w.f;
    w.i = u.y & 0xFFFF0000u; a[3] = w.f;
    w.i = u.z << 16;         a[4] = w.f;
    w.i = u.z & 0xFFFF0000u; a[5] = w.f;
    w.i = u.w << 16;         a[6] = w.f;
    w.i = u.w & 0xFFFF0000u; a[7] = w.f;
}

// Phase 1: block-local counting sort of EPB edges by SUPER-TILE (384 buckets,
// 256 nodes each). Block-private compact write (no global atomics, no
// scattered writes). aux[b*NST+st] = localOff(16b) | cnt<<16.
// Runs per (block,st) average 16 edges = 64B = one cache line.
__global__ __launch_bounds__(1024) void k_p1(const void* __restrict__ ei,
                                             unsigned int* __restrict__ aux,
                                             unsigned int* __restrict__ ebuf) {
    __shared__ unsigned int hl[NST];
    __shared__ unsigned int cur[NST];
    int t = threadIdx.x, b = blockIdx.x;
    if (t < NST) hl[t] = 0;
    __syncthreads();
    int is64 = detect64(ei);
    long e0 = (long)b * EPB;
    #pragma unroll
    for (int i = 0; i < EPB / 1024; ++i) {     // 6 iters
        int d = load_idx(ei, (long)Ee + e0 + i * 1024 + t, is64);
        atomicAdd(&hl[d >> 8], 1u);            // d / SN
    }
    __syncthreads();
    if (t < NST) cur[t] = hl[t];
    __syncthreads();
    // inclusive Hillis-Steele scan over 384
    for (int s = 1; s < NST; s <<= 1) {
        unsigned int v = (t < NST && t >= s) ? cur[t - s] : 0u;
        __syncthreads();
        if (t < NST) cur[t] += v;
        __syncthreads();
    }
    if (t < NST) {
        unsigned int ex = cur[t] - hl[t];      // exclusive
        aux[(long)b * NST + t] = ex | (hl[t] << 16);
        cur[t] = ex;                           // reuse as cursor
    }
    __syncthreads();
    #pragma unroll
    for (int i = 0; i < EPB / 1024; ++i) {     // re-read: block slice L2-hot
        long e = e0 + i * 1024 + t;
        int s = load_idx(ei, e, is64);
        int d = load_idx(ei, (long)Ee + e, is64);
        unsigned int pos = atomicAdd(&cur[d >> 8], 1u);   // LDS atomic
        ebuf[(long)b * EPB + pos] = (unsigned int)s | ((unsigned int)(d & (SN - 1)) << 17);
    }
}

// Phase 2: per super-tile, 256 threads. Thread t gathers block t's run (avg 16
// edges = one 64B line) into LDS, then count 256 local dsts (-> dinv, rowOff,
// rowEnd) and scatter src into the super-tile's packed srcs region.
// (Measured best of 3 variants: thread-per-run beat binary-search staging by
// ~6.5us across R4-R6 ledger.)
__global__ __launch_bounds__(256) void k_p2(const unsigned int* __restrict__ aux,
                                            const unsigned int* __restrict__ ebuf,
                                            unsigned int* __restrict__ rowOff,
                                            unsigned int* __restrict__ rowEnd,
                                            float* __restrict__ dinv,
                                            unsigned int* __restrict__ srcs) {
    __shared__ unsigned int stage[CAP_ST];   // 18.75 KB
    __shared__ unsigned int rb[HB];
    __shared__ unsigned int cnt[SN];
    __shared__ unsigned int sc[SN];
    __shared__ unsigned int cur[SN];
    int t = threadIdx.x, st = blockIdx.x;       // blockDim == HB == 256
    unsigned int av = aux[(long)t * NST + st];
    unsigned int roff = av & 0xFFFFu, rcnt = av >> 16;
    rb[t] = rcnt;
    __syncthreads();
    for (int s = 1; s < HB; s <<= 1) {          // inclusive scan over 256
        unsigned int v = (t >= s) ? rb[t - s] : 0u;
        __syncthreads();
        rb[t] += v;
        __syncthreads();
    }
    unsigned int mybase = rb[t] - rcnt;
    for (unsigned int i = 0; i < rcnt; ++i)
        stage[mybase + i] = ebuf[(long)t * EPB + roff + i];
    cnt[t] = 0;
    __syncthreads();
    int total = (int)rb[HB - 1];
    for (int i = t; i < total; i += 256)
        atomicAdd(&cnt[stage[i] >> 17], 1u);
    __syncthreads();
    sc[t] = cnt[t];
    __syncthreads();
    #pragma unroll
    for (int off = 1; off < SN; off <<= 1) {
        unsigned int v = (t >= off) ? sc[t - off] : 0u;
        __syncthreads();
        sc[t] += v;
        __syncthreads();
    }
    {
        unsigned int start = (unsigned int)(st * CAP_ST) + sc[t] - cnt[t];
        rowOff[(long)st * SN + t] = start;
        rowEnd[(long)st * SN + t] = start + cnt[t];
        cur[t] = start;
        dinv[(long)st * SN + t] = rsqrtf((float)(cnt[t] + 1));   // +1 self-loop
    }
    __syncthreads();
    for (int i = t; i < total; i += 256) {
        unsigned int u = stage[i];
        unsigned int pos = atomicAdd(&cur[u >> 17], 1u);
        srcs[pos] = u & 0x1FFFFu;
    }
}

// gb = bf16( (state @ conv_W) * dinv[row] )
__global__ __launch_bounds__(256) void k_gemm(const float* __restrict__ state,
                                              const float* __restrict__ W,
                                              const float* __restrict__ dinv,
                                              unsigned short* __restrict__ gb) {
    __shared__ float Wl[64 * 64];       // [k][c]
    __shared__ float Al[64 * 68];       // [r][k], stride 68
    int t = threadIdx.x;
    long n0 = (long)blockIdx.x * 64;

    const float4* W4 = (const float4*)W;
    float4* Wl4 = (float4*)Wl;
    #pragma unroll
    for (int i = 0; i < 4; ++i) Wl4[i * 256 + t] = W4[i * 256 + t];

    const float4* S4 = (const float4*)(state) + n0 * 16;
    #pragma unroll
    for (int i = 0; i < 4; ++i) {
        int f4 = t + i * 256;
        int r = f4 >> 4, k0 = (f4 & 15) * 4;
        *(float4*)(Al + r * 68 + k0) = S4[f4];
    }
    __syncthreads();

    int r0 = (t >> 4) * 4;
    int c0 = (t & 15) * 4;
    float acc[4][4] = {{0.f}};
    #pragma unroll
    for (int kk = 0; kk < 64; kk += 4) {
        float4 a4[4], w4[4];
        #pragma unroll
        for (int i = 0; i < 4; ++i) a4[i] = *(const float4*)(Al + (r0 + i) * 68 + kk);
        #pragma unroll
        for (int j = 0; j < 4; ++j) w4[j] = *(const float4*)(Wl + (kk + j) * 64 + c0);
        const float* aa = (const float*)a4;
        const float* ww = (const float*)w4;
        #pragma unroll
        for (int i = 0; i < 4; ++i)
            #pragma unroll
            for (int j = 0; j < 4; ++j) {
                float av = aa[i * 4 + j];
                #pragma unroll
                for (int c = 0; c < 4; ++c)
                    acc[i][c] = fmaf(av, ww[j * 4 + c], acc[i][c]);
            }
    }
    #pragma unroll
    for (int i = 0; i < 4; ++i) {
        long n = n0 + r0 + i;
        float dv = dinv[n];
        ushort4 o;
        o.x = f2bf(acc[i][0] * dv); o.y = f2bf(acc[i][1] * dv);
        o.z = f2bf(acc[i][2] * dv); o.w = f2bf(acc[i][3] * dv);
        *(ushort4*)(gb + n * 64 + c0) = o;
    }
}

// Fused gather + epilogue MLP. 512 threads (8 waves), GN=64 nodes/block.
// (Byte-exact R6 kernel -- measured optimum of 7 variants: 43.3us, VGPR 36,
// occ 50%. 4-wide 1-quad software pipeline; wave-local MLP, single block
// barrier after weight staging.)
__global__ __launch_bounds__(512) void k_gf(const unsigned int* __restrict__ rowOff,
                                            const unsigned int* __restrict__ rowEnd,
                                            const unsigned int* __restrict__ srcs,
                                            const unsigned short* __restrict__ gb,
                                            const float* __restrict__ dinv,
                                            const float* __restrict__ state,
                                            const float* __restrict__ conv_b,
                                            const float* __restrict__ W1,
                                            const float* __restrict__ b1,
                                            const float* __restrict__ W2,
                                            const float* __restrict__ b2,
                                            const float* __restrict__ W3,
                                            const float* __restrict__ b3,
                                            float* __restrict__ out) {
    __shared__ float sa[GN * 68];       // agg rows then x then h2 (17.4 KB)
    __shared__ float hs[GN * 34];       // h1 rows (8.7 KB)
    __shared__ float sW1[Cc * Hh];
    __shared__ float sW2[Hh * Hh];
    __shared__ float sW3[Hh], sb1[Hh], sb2[Hh], scb[Cc];
    __shared__ float sb3;
    int t = threadIdx.x;
    int wave = t >> 6, lane = t & 63;
    long n0 = (long)blockIdx.x * GN;

    for (int i = t; i < Cc * Hh; i += 512) sW1[i] = W1[i];
    for (int i = t; i < Hh * Hh; i += 512) sW2[i] = W2[i];
    if (t < Hh) { sW3[t] = W3[t]; sb1[t] = b1[t]; sb2[t] = b2[t]; }
    if (t >= 64 && t < 128) scb[t - 64] = conv_b[t - 64];
    if (t == 511) sb3 = b3[0];
    __syncthreads();    // the ONLY block barrier: weights visible to all waves

    // --- gather phase: group-per-node, uint4 per lane, pipelined 4-wide ---
    {
        int g = lane >> 3;              // node slot within wave
        int cs = lane & 7;              // 16B chunk: channels cs*8 .. cs*8+7
        int j = wave * 8 + g;
        long n = n0 + j;
        int ptr = (int)rowOff[n];
        int end = (int)rowEnd[n];
        float dv = dinv[n];
        const uint4* gb4 = (const uint4*)gb;    // row n = gb4[n*8 + cs]

        float a[8];
        set_u4(a, gb4[n * 8 + cs]);             // self-loop row

        int cnt = end - ptr;
        uint4 r0, r1, r2, r3;                   // in-flight row quad
        if (cnt >= 4) {                         // prologue: fill the pipe
            int s0 = (int)srcs[ptr];
            int s1 = (int)srcs[ptr + 1];
            int s2 = (int)srcs[ptr + 2];
            int s3 = (int)srcs[ptr + 3];
            r0 = gb4[(long)s0 * 8 + cs];
            r1 = gb4[(long)s1 * 8 + cs];
            r2 = gb4[(long)s2 * 8 + cs];
            r3 = gb4[(long)s3 * 8 + cs];
        }
        while (cnt >= 8) {
            int t0 = (int)srcs[ptr + 4];        // prefetch next idx quad
            int t1 = (int)srcs[ptr + 5];
            int t2 = (int)srcs[ptr + 6];
            int t3 = (int)srcs[ptr + 7];
            acc_u4(a, r0); acc_u4(a, r1);       // consume current rows
            acc_u4(a, r2); acc_u4(a, r3);
            r0 = gb4[(long)t0 * 8 + cs];        // issue next rows
            r1 = gb4[(long)t1 * 8 + cs];
            r2 = gb4[(long)t2 * 8 + cs];
            r3 = gb4[(long)t3 * 8 + cs];
            ptr += 4; cnt -= 4;
        }
        if (cnt >= 4) {                         // drain in-flight quad
            acc_u4(a, r0); acc_u4(a, r1);
            acc_u4(a, r2); acc_u4(a, r3);
            ptr += 4; cnt -= 4;
        }
        while (cnt > 0) {                       // scalar tail (<4 edges)
            int s0 = (int)srcs[ptr];
            uint4 u0 = gb4[(long)s0 * 8 + cs];
            acc_u4(a, u0);
            ++ptr; --cnt;
        }

        float* r = sa + j * 68 + cs * 8;        // 16B-aligned (68*4=272=17*16)
        float4 lo, hi;
        lo.x = a[0] * dv; lo.y = a[1] * dv; lo.z = a[2] * dv; lo.w = a[3] * dv;
        hi.x = a[4] * dv; hi.y = a[5] * dv; hi.z = a[6] * dv; hi.w = a[7] * dv;
        *(float4*)r = lo;
        *(float4*)(r + 4) = hi;
    }
    __builtin_amdgcn_wave_barrier();    // wave-local LDS ordering (in-order per wave)

    // --- 2a: x = relu(agg + cb) + state (wave-local: j = t>>3 in [8w,8w+8)) ---
    {
        int j = t >> 3, o = t & 7;
        long n = n0 + j;
        int k0 = o * 8;
        const float4* sp4 = (const float4*)(state + n * 64 + k0);
        float4 s0 = sp4[0], s1 = sp4[1];
        float* r = sa + j * 68 + k0;
        r[0] = fmaxf(r[0] + scb[k0 + 0], 0.f) + s0.x;
        r[1] = fmaxf(r[1] + scb[k0 + 1], 0.f) + s0.y;
        r[2] = fmaxf(r[2] + scb[k0 + 2], 0.f) + s0.z;
        r[3] = fmaxf(r[3] + scb[k0 + 3], 0.f) + s0.w;
        r[4] = fmaxf(r[4] + scb[k0 + 4], 0.f) + s1.x;
        r[5] = fmaxf(r[5] + scb[k0 + 5], 0.f) + s1.y;
        r[6] = fmaxf(r[6] + scb[k0 + 6], 0.f) + s1.z;
        r[7] = fmaxf(r[7] + scb[k0 + 7], 0.f) + s1.w;
    }
    __builtin_amdgcn_wave_barrier();

    // --- 2b: h1 = relu(x@W1 + b1) (wave-local) ---
    {
        int j = t >> 3, o = t & 7;
        int c0 = o * 4;
        float a0 = sb1[c0], a1 = sb1[c0 + 1], a2 = sb1[c0 + 2], a3 = sb1[c0 + 3];
        #pragma unroll
        for (int k = 0; k < Cc; ++k) {
            float xv = sa[j * 68 + k];
            float4 w = *(const float4*)(sW1 + k * Hh + c0);
            a0 = fmaf(xv, w.x, a0); a1 = fmaf(xv, w.y, a1);
            a2 = fmaf(xv, w.z, a2); a3 = fmaf(xv, w.w, a3);
        }
        float* r = hs + j * 34 + c0;
        r[0] = fmaxf(a0, 0.f); r[1] = fmaxf(a1, 0.f);
        r[2] = fmaxf(a2, 0.f); r[3] = fmaxf(a3, 0.f);
    }
    __builtin_amdgcn_wave_barrier();

    // --- 2c: h2 = relu(h1@W2 + b2) -> sa (wave-local) ---
    {
        int j = t >> 3, o = t & 7;
        int c0 = o * 4;
        float a0 = sb2[c0], a1 = sb2[c0 + 1], a2 = sb2[c0 + 2], a3 = sb2[c0 + 3];
        #pragma unroll
        for (int k = 0; k < Hh; ++k) {
            float xv = hs[j * 34 + k];
            float4 w = *(const float4*)(sW2 + k * Hh + c0);
            a0 = fmaf(xv, w.x, a0); a1 = fmaf(xv, w.y, a1);
            a2 = fmaf(xv, w.z, a2); a3 = fmaf(xv, w.w, a3);
        }
        float* r = sa + j * 68 + c0;
        r[0] = fmaxf(a0, 0.f); r[1] = fmaxf(a1, 0.f);
        r[2] = fmaxf(a2, 0.f); r[3] = fmaxf(a3, 0.f);
    }
    __builtin_amdgcn_wave_barrier();

    // --- 2d: y = h2@W3 + b3; softplus (wave-local: 8 lanes per node, shfl) ---
    {
        int g = lane >> 3, o = lane & 7;
        int j = wave * 8 + g;
        int k0 = o * 4;
        float y = 0.f;
        #pragma unroll
        for (int k = 0; k < 4; ++k) y = fmaf(sa[j * 68 + k0 + k], sW3[k0 + k], y);
        y += __shfl_xor(y, 1, 64);
        y += __shfl_xor(y, 2, 64);
        y += __shfl_xor(y, 4, 64);
        if (o == 0) {
            y += sb3;
            float sp = fmaxf(y, 0.f) + log1pf(expf(-fabsf(y)));
            out[n0 + j] = sp + 1e-20f;
        }
    }
}

extern "C" void kernel_launch(void* const* d_in, const int* in_sizes, int n_in,
                              void* d_out, int out_size, void* d_ws, size_t ws_size,
                              hipStream_t stream) {
    const float* state  = (const float*)d_in[0];
    const void*  ei     = d_in[1];
    const float* conv_W = (const float*)d_in[2];
    const float* conv_b = (const float*)d_in[3];
    const float* W1 = (const float*)d_in[4];
    const float* b1 = (const float*)d_in[5];
    const float* W2 = (const float*)d_in[6];
    const float* b2 = (const float*)d_in[7];
    const float* W3 = (const float*)d_in[8];
    const float* b3 = (const float*)d_in[9];
    float* out = (float*)d_out;

    float*          dinv   = (float*)d_ws;
    unsigned short* gb     = (unsigned short*)(dinv + Nn);
    unsigned int*   rowOff = (unsigned int*)(gb + (size_t)Nn * 64);
    unsigned int*   rowEnd = rowOff + Nn;
    unsigned int*   aux    = rowEnd + Nn;                    // HB*NST
    unsigned int*   ebuf   = aux + (size_t)HB * NST;         // Ee
    unsigned int*   srcs   = ebuf + Ee;                      // NST*CAP_ST

    k_p1<<<HB, 1024, 0, stream>>>(ei, aux, ebuf);
    k_p2<<<NST, 256, 0, stream>>>(aux, ebuf, rowOff, rowEnd, dinv, srcs);
    k_gemm<<<Nn / 64, 256, 0, stream>>>(state, conv_W, dinv, gb);
    k_gf<<<Nn / GN, 512, 0, stream>>>(rowOff, rowEnd, srcs, gb, dinv, state, conv_b,
                                      W1, b1, W2, b2, W3, b3, out);
}